// Round 9
// baseline (131.825 us; speedup 1.0000x reference)
//
#include <hip/hip_runtime.h>
#include <hip/hip_bf16.h>

typedef unsigned short u16;
typedef unsigned int u32;
typedef __bf16 bf16x8 __attribute__((ext_vector_type(8)));
typedef short s16x4 __attribute__((ext_vector_type(4)));
typedef short s16x8 __attribute__((ext_vector_type(8)));
typedef float floatx4 __attribute__((ext_vector_type(4)));

#define T_SEQ 2048
#define HDIM 64
#define NBH 32   // B*H

static __device__ __forceinline__ u16 f2b_rne(float x) {
    union { float f; u32 u; } c; c.f = x;
    u32 u = c.u;
    return (u16)((u + 0x7fffu + ((u >> 16) & 1u)) >> 16);
}
static __device__ __forceinline__ u32 fbits(float x) {
    union { float f; u32 u; } c; c.f = x;
    return c.u;
}

// async 16B/lane global->LDS; LDS dest = wave-uniform base + lane*16
#define GLOAD_LDS16(gp, lp)                                                      \
    __builtin_amdgcn_global_load_lds(                                            \
        (const __attribute__((address_space(1))) u32*)(gp),                      \
        (__attribute__((address_space(3))) u32*)(lp), 16, 0, 0)

// ---- prepass (round-5 proven): K fp32->bf16 flat; V fp32->bf16 transposed
// [BH,D,T] with column permutation pos(k) = qg*16 + (t>>1)*8 + (t&1)*4 + j
// (per 64-key window) so PV B-frag t-pairs are contiguous 16B in LDS. ----
__global__ __launch_bounds__(256) void prep(const float* __restrict__ k,
                                            const float* __restrict__ v,
                                            u16* __restrict__ kb,
                                            u16* __restrict__ vt) {
    __shared__ u16 tile[64][68];
    const int bh = blockIdx.y, t0 = blockIdx.x * 64;
    const int tid = threadIdx.x;

    const float* ksrc = k + ((size_t)bh * T_SEQ + t0) * HDIM;
    u16* kdst = kb + ((size_t)bh * T_SEQ + t0) * HDIM;
#pragma unroll
    for (int p = 0; p < 4; p++) {
        int idx = p * 256 + tid;
        float4 f = ((const float4*)ksrc)[idx];
        ushort4 o;
        o.x = f2b_rne(f.x); o.y = f2b_rne(f.y); o.z = f2b_rne(f.z); o.w = f2b_rne(f.w);
        ((ushort4*)kdst)[idx] = o;
    }

    const float* vsrc = v + ((size_t)bh * T_SEQ + t0) * HDIM;
#pragma unroll
    for (int p = 0; p < 4; p++) {
        int idx = p * 256 + tid;
        int r = idx >> 4, c4 = (idx & 15) * 4;
        float4 f = *(const float4*)(vsrc + r * HDIM + c4);
        tile[c4 + 0][r] = f2b_rne(f.x);
        tile[c4 + 1][r] = f2b_rne(f.y);
        tile[c4 + 2][r] = f2b_rne(f.z);
        tile[c4 + 3][r] = f2b_rne(f.w);
    }
    __syncthreads();
    u16* dst = vt + (size_t)bh * HDIM * T_SEQ + t0;
#pragma unroll
    for (int p = 0; p < 4; p++) {
        int idx = p * 256 + tid;
        int d = idx >> 4, c4 = (idx & 15) * 4;
        int t = c4 >> 4, qg = (c4 >> 2) & 3;
        int pos = qg * 16 + (t >> 1) * 8 + (t & 1) * 4;
        *(ushort4*)(dst + (size_t)d * T_SEQ + pos) = *(ushort4*)(&tile[d][c4]);
    }
}

// ---- main kernel: dual-q-tile blocks ----
// grid (bh=32, p=16): block owns q-tiles p (small, qts) AND 31-p (big, qtb).
// One key sweep j=0..qtb: big tile computed every iter, small tile while
// j<=qts. Every block = exactly 33 64x64 work-units -> near-equal durations,
// no solo-tail. On dual iters each K/V LDS fragment feeds both tiles.
// S^T = K*Q^T so the QK C-frag IS the PV A-frag (no P LDS round-trip).
// Staging: async global_load_lds, double-buffered, swizzles folded into
// per-lane SOURCE addresses (round-5 proven).
__global__ __launch_bounds__(256, 2) void fattn(const float* __restrict__ q,
                                                const u16* __restrict__ kb,
                                                const u16* __restrict__ vtb,
                                                float* __restrict__ out) {
    __shared__ __align__(16) u16 Kl[2][64 * 64];   // [key][d], XOR slot swizzle
    __shared__ __align__(16) u16 Vl[2][64 * 64];   // [d][perm-key], +d slot swizzle

    const int bh = blockIdx.x;
    const int p = blockIdx.y;                      // 0..15, heavy (p=0) first
    const int qtb = 31 - p;                        // big tile
    const int qts = p;                             // small tile
    const int iters = qtb + 1;
    const int tid = threadIdx.x;
    const int wave = tid >> 6, lane = tid & 63;
    const int l15 = lane & 15, quad = lane >> 4;

    const float* qp = q + (size_t)bh * T_SEQ * HDIM;
    const u16* kp = kb + (size_t)bh * T_SEQ * HDIM;
    const u16* vp = vtb + (size_t)bh * HDIM * T_SEQ;

    // staging: lane covers LDS bytes [wave*1024 + lane*16] (+4096 for issue 1)
    const int srow = wave * 8 + (lane >> 3);
    const int slot = lane & 7;
    const u16* kg0 = kp + srow * HDIM + (slot ^ (srow & 7)) * 8;
    const int vs = (slot - srow) & 7;
    const u16* vg0 = vp + (size_t)srow * T_SEQ + vs * 8;
    const u16* vg1 = vp + (size_t)(srow + 32) * T_SEQ + vs * 8;

    auto stage = [&](int j, int buf) {
        const u16* ks = kg0 + j * 64 * HDIM;
        u16* Kd = &Kl[buf][wave * 512];
        GLOAD_LDS16(ks, Kd);
        GLOAD_LDS16(ks + 32 * HDIM, Kd + 2048);
        u16* Vd = &Vl[buf][wave * 512];
        GLOAD_LDS16(vg0 + j * 64, Vd);
        GLOAD_LDS16(vg1 + j * 64, Vd + 2048);
    };

    stage(0, 0);   // prologue (async)

    // Q B-frags: qn=0 -> big tile rows, qn=1 -> small tile rows
    const float SL2E = 0.125f * 1.44269504088896f;
    bf16x8 qf[2][2];
#pragma unroll
    for (int qn = 0; qn < 2; qn++) {
        const int base = (qn ? qts : qtb) * 64 + wave * 16;
        const float* qrow = qp + (size_t)(base + l15) * HDIM;
#pragma unroll
        for (int kc = 0; kc < 2; kc++) {
            const float4* p4 = (const float4*)(qrow + kc * 32 + quad * 8);
            float4 fa = p4[0], fb = p4[1];
            union { bf16x8 v; u16 s[8]; } cv;
            cv.s[0] = f2b_rne(fa.x * SL2E); cv.s[1] = f2b_rne(fa.y * SL2E);
            cv.s[2] = f2b_rne(fa.z * SL2E); cv.s[3] = f2b_rne(fa.w * SL2E);
            cv.s[4] = f2b_rne(fb.x * SL2E); cv.s[5] = f2b_rne(fb.y * SL2E);
            cv.s[6] = f2b_rne(fb.z * SL2E); cv.s[7] = f2b_rne(fb.w * SL2E);
            qf[qn][kc] = cv.v;
        }
    }

    floatx4 o_acc[2][4];
#pragma unroll
    for (int qn = 0; qn < 2; qn++)
#pragma unroll
        for (int dt = 0; dt < 4; dt++) o_acc[qn][dt] = (floatx4){0.f, 0.f, 0.f, 0.f};
    float lsum[2] = {0.f, 0.f};
    const floatx4 ZERO4 = {0.f, 0.f, 0.f, 0.f};

    for (int j = 0; j < iters; ++j) {
        const int cur = j & 1;
        __syncthreads();   // vmcnt drain + barrier: buf[cur] staged

        if (j + 1 < iters) stage(j + 1, cur ^ 1);  // async prefetch

        const u16* Kc = Kl[cur];
        const u16* Vc = Vl[cur];
        const bool dual = (j <= qts);

        // S^T = K * Q^T : A = K-frag (m=key), B = qf (n=qrow)
        floatx4 sacc[2][4];
        if (dual) {
#pragma unroll
            for (int kt = 0; kt < 4; kt++) {
                int rk = kt * 16 + l15;
                bf16x8 kf0 = *(const bf16x8*)(Kc + rk * 64 + ((quad) ^ (rk & 7)) * 8);
                sacc[0][kt] = __builtin_amdgcn_mfma_f32_16x16x32_bf16(kf0, qf[0][0], ZERO4, 0, 0, 0);
                sacc[1][kt] = __builtin_amdgcn_mfma_f32_16x16x32_bf16(kf0, qf[1][0], ZERO4, 0, 0, 0);
                bf16x8 kf1 = *(const bf16x8*)(Kc + rk * 64 + ((4 + quad) ^ (rk & 7)) * 8);
                sacc[0][kt] = __builtin_amdgcn_mfma_f32_16x16x32_bf16(kf1, qf[0][1], sacc[0][kt], 0, 0, 0);
                sacc[1][kt] = __builtin_amdgcn_mfma_f32_16x16x32_bf16(kf1, qf[1][1], sacc[1][kt], 0, 0, 0);
            }
        } else {
#pragma unroll
            for (int kt = 0; kt < 4; kt++) {
                int rk = kt * 16 + l15;
                bf16x8 kf0 = *(const bf16x8*)(Kc + rk * 64 + ((quad) ^ (rk & 7)) * 8);
                sacc[0][kt] = __builtin_amdgcn_mfma_f32_16x16x32_bf16(kf0, qf[0][0], ZERO4, 0, 0, 0);
                bf16x8 kf1 = *(const bf16x8*)(Kc + rk * 64 + ((4 + quad) ^ (rk & 7)) * 8);
                sacc[0][kt] = __builtin_amdgcn_mfma_f32_16x16x32_bf16(kf1, qf[0][1], sacc[0][kt], 0, 0, 0);
            }
        }

        // P^T = exp2(S^T); v_perm pack (trunc); mask only on each tile's diag iter
        s16x4 pf[2][4];
        const int nq = dual ? 2 : 1;
#pragma unroll
        for (int qn = 0; qn < 2; qn++) {
            if (qn >= nq) break;
            const bool diag = (j == (qn ? qts : qtb));
            const int rhs = wave * 16 + l15;
#pragma unroll
            for (int kt = 0; kt < 4; kt++) {
                float e0 = __builtin_amdgcn_exp2f(sacc[qn][kt][0]);
                float e1 = __builtin_amdgcn_exp2f(sacc[qn][kt][1]);
                float e2 = __builtin_amdgcn_exp2f(sacc[qn][kt][2]);
                float e3 = __builtin_amdgcn_exp2f(sacc[qn][kt][3]);
                if (diag) {
                    int kl = kt * 16 + quad * 4;
                    if (kl + 0 > rhs) e0 = 0.f;
                    if (kl + 1 > rhs) e1 = 0.f;
                    if (kl + 2 > rhs) e2 = 0.f;
                    if (kl + 3 > rhs) e3 = 0.f;
                }
                lsum[qn] += (e0 + e1) + (e2 + e3);
                union { s16x4 v; u32 w[2]; } pk;
                pk.w[0] = __builtin_amdgcn_perm(fbits(e1), fbits(e0), 0x07060302u);
                pk.w[1] = __builtin_amdgcn_perm(fbits(e3), fbits(e2), 0x07060302u);
                pf[qn][kt] = pk.v;
            }
        }

        // O += P * V : A = pf (regs), B = V-frag (b128 covers kt-pair)
        if (dual) {
#pragma unroll
            for (int tp = 0; tp < 2; tp++)
#pragma unroll
                for (int dt = 0; dt < 4; dt++) {
                    int d = dt * 16 + l15;
                    int sl = (quad * 2 + tp + d) & 7;
                    s16x8 vfx = *(const s16x8*)(Vc + d * 64 + sl * 8);
                    s16x4 v0 = __builtin_shufflevector(vfx, vfx, 0, 1, 2, 3);
                    s16x4 v1 = __builtin_shufflevector(vfx, vfx, 4, 5, 6, 7);
                    o_acc[0][dt] = __builtin_amdgcn_mfma_f32_16x16x16bf16_1k(pf[0][2 * tp], v0, o_acc[0][dt], 0, 0, 0);
                    o_acc[0][dt] = __builtin_amdgcn_mfma_f32_16x16x16bf16_1k(pf[0][2 * tp + 1], v1, o_acc[0][dt], 0, 0, 0);
                    o_acc[1][dt] = __builtin_amdgcn_mfma_f32_16x16x16bf16_1k(pf[1][2 * tp], v0, o_acc[1][dt], 0, 0, 0);
                    o_acc[1][dt] = __builtin_amdgcn_mfma_f32_16x16x16bf16_1k(pf[1][2 * tp + 1], v1, o_acc[1][dt], 0, 0, 0);
                }
        } else {
#pragma unroll
            for (int tp = 0; tp < 2; tp++)
#pragma unroll
                for (int dt = 0; dt < 4; dt++) {
                    int d = dt * 16 + l15;
                    int sl = (quad * 2 + tp + d) & 7;
                    s16x8 vfx = *(const s16x8*)(Vc + d * 64 + sl * 8);
                    s16x4 v0 = __builtin_shufflevector(vfx, vfx, 0, 1, 2, 3);
                    s16x4 v1 = __builtin_shufflevector(vfx, vfx, 4, 5, 6, 7);
                    o_acc[0][dt] = __builtin_amdgcn_mfma_f32_16x16x16bf16_1k(pf[0][2 * tp], v0, o_acc[0][dt], 0, 0, 0);
                    o_acc[0][dt] = __builtin_amdgcn_mfma_f32_16x16x16bf16_1k(pf[0][2 * tp + 1], v1, o_acc[0][dt], 0, 0, 0);
                }
        }
    }

    // epilogue: per tile, reduce lsum over quads, redistribute, store O/l
    float* op = out + (size_t)bh * T_SEQ * HDIM;
#pragma unroll
    for (int qn = 0; qn < 2; qn++) {
        float tot = lsum[qn];
        tot += __shfl_xor(tot, 16, 64);
        tot += __shfl_xor(tot, 32, 64);            // lane holds sum for qrow=l15
        const int base = (qn ? qts : qtb) * 64 + wave * 16;
#pragma unroll
        for (int rg = 0; rg < 4; rg++) {
            float inv = 1.0f / __shfl(tot, quad * 4 + rg, 64);
            size_t row = (size_t)(base + quad * 4 + rg) * HDIM;
#pragma unroll
            for (int dt = 0; dt < 4; dt++)
                op[row + dt * 16 + l15] = o_acc[qn][dt][rg] * inv;
        }
    }
}

extern "C" void kernel_launch(void* const* d_in, const int* in_sizes, int n_in,
                              void* d_out, int out_size, void* d_ws, size_t ws_size,
                              hipStream_t stream) {
    const float* q = (const float*)d_in[0];
    const float* k = (const float*)d_in[1];
    const float* v = (const float*)d_in[2];
    float* out = (float*)d_out;

    u16* kb = (u16*)d_ws;                               // 8 MB bf16 K
    u16* vt = kb + (size_t)NBH * T_SEQ * HDIM;          // 8 MB bf16 V^T (permuted)

    prep<<<dim3(T_SEQ / 64, NBH), 256, 0, stream>>>(k, v, kb, vt);
    fattn<<<dim3(NBH, 16), 256, 0, stream>>>(q, kb, vt, out);
}